// Round 5
// baseline (439.651 us; speedup 1.0000x reference)
//
#include <hip/hip_runtime.h>

// ---------- common helpers ----------
typedef short bf16x8 __attribute__((ext_vector_type(8)));
typedef float f32x4 __attribute__((ext_vector_type(4)));

__device__ __forceinline__ void async16(const void* g, const void* l) {
  __builtin_amdgcn_global_load_lds(
      (const __attribute__((address_space(1))) unsigned int*)g,
      (__attribute__((address_space(3))) unsigned int*)(void*)(uintptr_t)l,
      16, 0, 0);
}

__device__ __forceinline__ unsigned short f2b(float f) {
  unsigned int u = __float_as_uint(f);
  u += 0x7fffu + ((u >> 16) & 1u);   // round-to-nearest-even
  return (unsigned short)(u >> 16);
}
__device__ __forceinline__ unsigned short f2b_trunc(float f) {
  return (unsigned short)(__float_as_uint(f) >> 16);
}

// ---------- cast fp32 -> bf16, n % 1024 == 0 ----------
__global__ __launch_bounds__(256) void cast_f32_bf16(
    const float* __restrict__ in, unsigned short* __restrict__ out, int n) {
  int i = (blockIdx.x * 256 + threadIdx.x) * 4;
  if (i < n) {
    float4 v = *(const float4*)(in + i);
    ushort4 o;
    o.x = f2b(v.x); o.y = f2b(v.y); o.z = f2b(v.z); o.w = f2b(v.w);
    *(ushort4*)(out + i) = o;
  }
}

// ---------- transpose+cast: out_bf16[N][K] = in_f32[K][N], K,N multiples of 64 ----------
__global__ __launch_bounds__(256) void transpose_cast(
    const float* __restrict__ in, unsigned short* __restrict__ out,
    int K, int N) {
  __shared__ __align__(16) unsigned short tile[64][65];
  const int k0 = blockIdx.y * 64, n0 = blockIdx.x * 64;
  const int tid = threadIdx.x;
  const int r = tid >> 4, c4 = tid & 15;
#pragma unroll
  for (int p = 0; p < 4; ++p) {
    int row = p * 16 + r;
    float4 v = *(const float4*)(in + (size_t)(k0 + row) * N + n0 + c4 * 4);
    tile[c4 * 4 + 0][row] = f2b(v.x);
    tile[c4 * 4 + 1][row] = f2b(v.y);
    tile[c4 * 4 + 2][row] = f2b(v.z);
    tile[c4 * 4 + 3][row] = f2b(v.w);
  }
  __syncthreads();
#pragma unroll
  for (int p = 0; p < 4; ++p) {
    int nr = p * 16 + r;
    ushort4 o;
    o.x = tile[nr][c4 * 4 + 0];
    o.y = tile[nr][c4 * 4 + 1];
    o.z = tile[nr][c4 * 4 + 2];
    o.w = tile[nr][c4 * 4 + 3];
    *(ushort4*)(out + (size_t)(n0 + nr) * K + k0 + c4 * 4) = o;
  }
}

// ---------- transpose bf16: out[N][K] = in[K][N], K,N multiples of 64 ----------
__global__ __launch_bounds__(256) void transpose_bf16(
    const unsigned short* __restrict__ in, unsigned short* __restrict__ out,
    int K, int N) {
  __shared__ __align__(16) unsigned short tile[64][65];
  const int k0 = blockIdx.y * 64, n0 = blockIdx.x * 64;
  const int tid = threadIdx.x;
  const int r = tid >> 4, c4 = tid & 15;
#pragma unroll
  for (int p = 0; p < 4; ++p) {
    int row = p * 16 + r;
    ushort4 v = *(const ushort4*)(in + (size_t)(k0 + row) * N + n0 + c4 * 4);
    tile[c4 * 4 + 0][row] = v.x;
    tile[c4 * 4 + 1][row] = v.y;
    tile[c4 * 4 + 2][row] = v.z;
    tile[c4 * 4 + 3][row] = v.w;
  }
  __syncthreads();
#pragma unroll
  for (int p = 0; p < 4; ++p) {
    int nr = p * 16 + r;
    ushort4 o;
    o.x = tile[nr][c4 * 4 + 0];
    o.y = tile[nr][c4 * 4 + 1];
    o.z = tile[nr][c4 * 4 + 2];
    o.w = tile[nr][c4 * 4 + 3];
    *(ushort4*)(out + (size_t)(n0 + nr) * K + k0 + c4 * 4) = o;
  }
}

// ---------- GEMM: C[M,N] = alpha * A[M,K] @ BT[N,K]^T (bf16 in, fp32 accum) ----------
__global__ __launch_bounds__(256) void gemm_bt(
    const unsigned short* __restrict__ A, const unsigned short* __restrict__ BT,
    unsigned short* __restrict__ Cb, float* __restrict__ Cf, int M, int N, int K,
    float alpha) {
  __shared__ __align__(16) unsigned short sA[128 * 64];
  __shared__ __align__(16) unsigned short sB[128 * 64];
  const int tid = threadIdx.x;
  const int wave = tid >> 6, lane = tid & 63;
  const int quad = lane >> 4, cl = lane & 15;
  const int m0 = blockIdx.y * 128, n0 = blockIdx.x * 128;
  const int wm = (wave >> 1) * 64, wn = (wave & 1) * 64;
  (void)M;

  f32x4 acc[4][4] = {};

  const unsigned short* gA = A + (size_t)(m0 + wave * 32 + (lane >> 3)) * K + (lane & 7) * 8;
  const unsigned short* gB = BT + (size_t)(n0 + wave * 32 + (lane >> 3)) * K + (lane & 7) * 8;
  char* lA = (char*)sA + (wave * 32) * 128;
  char* lB = (char*)sB + (wave * 32) * 128;

  for (int kt = 0; kt < K; kt += 64) {
#pragma unroll
    for (int r = 0; r < 4; ++r) {
      async16(gA + (size_t)r * 8 * K + kt, lA + r * 8 * 128);
      async16(gB + (size_t)r * 8 * K + kt, lB + r * 8 * 128);
    }
    __syncthreads();
#pragma unroll
    for (int kk = 0; kk < 64; kk += 32) {
      bf16x8 af[4], bfr[4];
#pragma unroll
      for (int i = 0; i < 4; ++i)
        af[i] = *(const bf16x8*)((const char*)sA + (wm + i * 16 + cl) * 128 + kk * 2 + quad * 16);
#pragma unroll
      for (int j = 0; j < 4; ++j)
        bfr[j] = *(const bf16x8*)((const char*)sB + (wn + j * 16 + cl) * 128 + kk * 2 + quad * 16);
#pragma unroll
      for (int i = 0; i < 4; ++i)
#pragma unroll
        for (int j = 0; j < 4; ++j)
          acc[i][j] = __builtin_amdgcn_mfma_f32_16x16x32_bf16(af[i], bfr[j], acc[i][j], 0, 0, 0);
    }
    __syncthreads();
  }
#pragma unroll
  for (int i = 0; i < 4; ++i)
#pragma unroll
    for (int j = 0; j < 4; ++j)
#pragma unroll
      for (int r = 0; r < 4; ++r) {
        int row = m0 + wm + i * 16 + quad * 4 + r;
        int col = n0 + wn + j * 16 + cl;
        float v = acc[i][j][r] * alpha;
        if (Cb) Cb[(size_t)row * N + col] = f2b(v);
        if (Cf) Cf[(size_t)row * N + col] = v;
      }
}

// ---------- flash-style causal attention, v4 ----------
// grid (H, T/128, B) = (16,16,2), 512 threads (8 waves).
// Block handles q-tile pair {31-j (waves 0-3), j (waves 4-7)}, sharing one
// k-loop + K/V staging. Uniform issue-work per block. Q pre-scaled by
// 1/sqrt(128)*log2(e) at the Q-GEMM epilogue; softmax in exp2 domain.
// Row-sums come from an MFMA against a ones-matrix on the stored bf16 P.
// LDS 48KB: sK 16K + sVT 16K + sP 2x8K.
__global__ __launch_bounds__(512) void mla_attn(
    const unsigned short* __restrict__ Qm, const unsigned short* __restrict__ Km,
    const unsigned short* __restrict__ Vt, unsigned short* __restrict__ Om, int T) {
  const int ld = 2048;
  const int ldv = 4096;  // B*T
  __shared__ __align__(16) unsigned short sK[64 * 128];   // [t][d] 16 chunks/row, xor-swizzled
  __shared__ __align__(16) unsigned short sVT[128 * 64];  // [d][t] 8 chunks/row, xor-swizzled
  __shared__ __align__(16) unsigned short sP[2][64 * 64]; // per-group [q][t] 8 chunks/row
  const int h = blockIdx.x, j = blockIdx.y, b = blockIdx.z;
  const int tid = threadIdx.x, wave = tid >> 6, lane = tid & 63;
  const int quad = lane >> 4, cl = lane & 15;
  const int grp = wave >> 2, w4 = wave & 3;
  const int qt = grp ? j : (31 - j);      // group 0 = heavy tile
  const int qt_heavy = 31 - j;

  // Q A-fragments in registers (already scaled by 1/sqrt(d)*log2e)
  bf16x8 qf[4];
  {
    const unsigned short* Qg =
        Qm + (size_t)(b * T + qt * 64 + w4 * 16 + cl) * ld + h * 128 + quad * 8;
#pragma unroll
    for (int kk = 0; kk < 4; ++kk)
      qf[kk] = *(const bf16x8*)(Qg + kk * 32);
  }

  bf16x8 vones;
#pragma unroll
  for (int z = 0; z < 8; ++z) vones[z] = (short)0x3f80;  // bf16 1.0

  float m_i[4], l_i[4];
  f32x4 acc_o[8] = {};
#pragma unroll
  for (int r = 0; r < 4; ++r) { m_i[r] = -1e30f; l_i[r] = 0.f; }

  for (int kt = 0; kt <= qt_heavy; ++kt) {
    const unsigned short* Kg = Km + (size_t)(b * T + kt * 64) * ld + h * 128;
    const unsigned short* Vg = Vt + (size_t)(h * 128) * ldv + (size_t)b * T + kt * 64;
    __syncthreads();  // previous tile's sK/sVT reads complete
#pragma unroll
    for (int r = 0; r < 2; ++r) {
      int c0 = (r * 8 + wave) * 64;
      int c = c0 + lane;
      int row = c >> 4, jj = (c & 15) ^ (row & 7);
      async16(Kg + (size_t)row * ld + jj * 8, (char*)sK + c0 * 16);
      int d = c >> 3, jv = (c & 7) ^ (d & 7);
      async16(Vg + (size_t)d * ldv + jv * 8, (char*)sVT + c0 * 16);
    }
    __syncthreads();  // staging complete

    if (kt <= qt) {  // wave-uniform guard (group-level)
      // S = Q @ K^T : 16 q-rows (this wave) x 64 keys, exp2-domain logits
      f32x4 s[4] = {};
#pragma unroll
      for (int kk = 0; kk < 4; ++kk) {
#pragma unroll
        for (int jt = 0; jt < 4; ++jt) {
          int t = jt * 16 + cl;
          int jp = (kk * 4 + quad) ^ (t & 7);
          bf16x8 bk = *(const bf16x8*)((const char*)sK + (t * 16 + jp) * 16);
          s[jt] = __builtin_amdgcn_mfma_f32_16x16x32_bf16(qf[kk], bk, s[jt], 0, 0, 0);
        }
      }

      // causal mask + online max update
      const bool need_mask = (kt == qt);
      float alpha_r[4];
#pragma unroll
      for (int r = 0; r < 4; ++r) {
        int q_l = w4 * 16 + quad * 4 + r;
        float mx = -1e30f;
#pragma unroll
        for (int jt = 0; jt < 4; ++jt) {
          float v = s[jt][r];
          if (need_mask) {
            int t_l = jt * 16 + cl;
            if (t_l > q_l) v = -1e30f;
          }
          s[jt][r] = v;
          mx = fmaxf(mx, v);
        }
#pragma unroll
        for (int off = 1; off < 16; off <<= 1)
          mx = fmaxf(mx, __shfl_xor(mx, off));
        float m_new = fmaxf(m_i[r], mx);
        alpha_r[r] = exp2f(m_i[r] - m_new);
        m_i[r] = m_new;
#pragma unroll
        for (int jt = 0; jt < 4; ++jt)
          s[jt][r] = exp2f(s[jt][r] - m_new);
      }

      // rescale accumulator (vectorized; compiler can pack)
      f32x4 av = {alpha_r[0], alpha_r[1], alpha_r[2], alpha_r[3]};
#pragma unroll
      for (int jd = 0; jd < 8; ++jd) acc_o[jd] *= av;

      // write P (bf16, trunc) swizzled into this group's sP
#pragma unroll
      for (int jt = 0; jt < 4; ++jt)
#pragma unroll
        for (int r = 0; r < 4; ++r) {
          int q = w4 * 16 + quad * 4 + r;
          int swz = (q & 7) ^ (((q >> 3) & 1) << 1);
          int t = jt * 16 + cl;
          int jp = (t >> 3) ^ swz;
          sP[grp][(q * 8 + jp) * 8 + (t & 7)] = f2b_trunc(s[jt][r]);
        }

      // O += P @ V ; row-sums via MFMA with ones-matrix (consistent with stored P)
      f32x4 acc_l = {};
#pragma unroll
      for (int kk2 = 0; kk2 < 2; ++kk2) {
        int q = w4 * 16 + cl;
        int swz = (q & 7) ^ (((q >> 3) & 1) << 1);
        int jp = (kk2 * 4 + quad) ^ swz;
        bf16x8 ap = *(const bf16x8*)((const char*)&sP[grp][0] + (q * 8 + jp) * 16);
        acc_l = __builtin_amdgcn_mfma_f32_16x16x32_bf16(ap, vones, acc_l, 0, 0, 0);
#pragma unroll
        for (int jd = 0; jd < 8; ++jd) {
          int d = jd * 16 + cl;
          int jpv = (kk2 * 4 + quad) ^ (d & 7);
          bf16x8 bv = *(const bf16x8*)((const char*)sVT + (d * 8 + jpv) * 16);
          acc_o[jd] = __builtin_amdgcn_mfma_f32_16x16x32_bf16(ap, bv, acc_o[jd], 0, 0, 0);
        }
      }
#pragma unroll
      for (int r = 0; r < 4; ++r)
        l_i[r] = l_i[r] * alpha_r[r] + acc_l[r];
    }
  }

  // epilogue: normalize and store this wave's 16-row strip
#pragma unroll
  for (int r = 0; r < 4; ++r) {
    float inv = 1.f / l_i[r];
    int row = b * T + qt * 64 + w4 * 16 + quad * 4 + r;
#pragma unroll
    for (int jd = 0; jd < 8; ++jd)
      Om[(size_t)row * ld + h * 128 + jd * 16 + cl] = f2b(acc_o[jd][r] * inv);
  }
}

// ---------- launch ----------
extern "C" void kernel_launch(void* const* d_in, const int* in_sizes, int n_in,
                              void* d_out, int out_size, void* d_ws, size_t ws_size,
                              hipStream_t stream) {
  (void)in_sizes; (void)n_in; (void)out_size; (void)ws_size;
  const int B = 2, T = 2048, Dm = 2048, H = 16, Dh = 128, R = 512;
  const int M = B * T;  // 4096
  const float* x     = (const float*)d_in[0];
  const float* Wq    = (const float*)d_in[1];
  const float* Wdown = (const float*)d_in[2];
  const float* Wkup  = (const float*)d_in[3];
  const float* Wvup  = (const float*)d_in[4];
  const float* Wo    = (const float*)d_in[5];

  float* out  = (float*)d_out;                      // (B*T) x 2048 fp32
  float* cout = out + (size_t)M * Dm;               // (B*T) x 512  fp32

  unsigned short* ws  = (unsigned short*)d_ws;      // bf16 scratch
  unsigned short* WqT = ws;                         // 2048x2048
  unsigned short* WoT = WqT + (size_t)Dm * Dm;      // 2048x2048
  unsigned short* WdT = WoT + (size_t)Dm * Dm;      // 512x2048
  unsigned short* WkT = WdT + (size_t)R * Dm;       // 2048x512
  unsigned short* WvT = WkT + (size_t)Dm * R;       // 2048x512
  unsigned short* xb  = WvT + (size_t)Dm * R;       // 4096x2048 (reused as AO)
  unsigned short* cb  = xb + (size_t)M * Dm;        // 4096x512
  unsigned short* Qb  = cb + (size_t)M * R;         // 4096x2048
  unsigned short* Kb  = Qb + (size_t)M * Dm;
  unsigned short* Vb  = Kb + (size_t)M * Dm;
  unsigned short* Vtb = Vb + (size_t)M * Dm;        // 2048x4096 (V^T, d-major)
  unsigned short* AO  = xb;                         // alias: xb dead after Q-proj

  // softmax scale folded into Q: 1/sqrt(128) * log2(e)
  const float scale2 = 0.08838834764831845f * 1.4426950408889634f;

  // input casts / weight transposes -> bf16 BT form
  cast_f32_bf16<<<(M * Dm) / 1024, 256, 0, stream>>>(x, xb, M * Dm);
  transpose_cast<<<dim3(32, 32), 256, 0, stream>>>(Wq, WqT, Dm, Dm);
  transpose_cast<<<dim3(32, 32), 256, 0, stream>>>(Wo, WoT, Dm, Dm);
  transpose_cast<<<dim3(8, 32), 256, 0, stream>>>(Wdown, WdT, Dm, R);
  transpose_cast<<<dim3(32, 8), 256, 0, stream>>>(Wkup, WkT, R, Dm);
  transpose_cast<<<dim3(32, 8), 256, 0, stream>>>(Wvup, WvT, R, Dm);

  // projections (Q pre-scaled)
  gemm_bt<<<dim3(R / 128, M / 128), 256, 0, stream>>>(xb, WdT, cb, cout, M, R, Dm, 1.0f);
  gemm_bt<<<dim3(Dm / 128, M / 128), 256, 0, stream>>>(xb, WqT, Qb, nullptr, M, Dm, Dm, scale2);
  gemm_bt<<<dim3(Dm / 128, M / 128), 256, 0, stream>>>(cb, WkT, Kb, nullptr, M, Dm, R, 1.0f);
  gemm_bt<<<dim3(Dm / 128, M / 128), 256, 0, stream>>>(cb, WvT, Vb, nullptr, M, Dm, R, 1.0f);

  // V -> V^T (d-major) for conflict-free PV B-fragments
  transpose_bf16<<<dim3(Dm / 64, M / 64), 256, 0, stream>>>(Vb, Vtb, M, Dm);

  // causal attention: grid (h, pair, b); same-h blocks land on one XCD
  mla_attn<<<dim3(H, T / 128, B), 512, 0, stream>>>(Qb, Kb, Vtb, AO, T);

  // output projection (fp32 out)
  gemm_bt<<<dim3(Dm / 128, M / 128), 256, 0, stream>>>(AO, WoT, nullptr, out, M, Dm, Dm, 1.0f);
  (void)Dh; (void)H;
}